// Round 3
// baseline (156.502 us; speedup 1.0000x reference)
//
#include <hip/hip_runtime.h>

// Problem constants (from reference)
constexpr int NUM_BIN  = 64;
constexpr int NUM_CAT  = 1024;   // 64 groups x 16
constexpr int NUM_NUM  = 4096;   // 256 groups x 16
constexpr int IN1_C    = NUM_BIN + NUM_CAT + NUM_NUM;   // 5184
constexpr int IN2_C    = 64 + 64 + 256;                 // 384
constexpr int BATCH_C  = 16384;

typedef float f32x4 __attribute__((ext_vector_type(4)));

// ---------------------------------------------------------------------------
// Kernel 1: eff_w[c] = w1[c] * w2[j(c)] ;  cst = sum_c b1[c]*w2[j(c)] + sum_j b2[j]
// Single block, 1024 threads. Fully overwrites its workspace region each call.
// ---------------------------------------------------------------------------
__global__ __launch_bounds__(1024) void pwl_prep(
    const float* __restrict__ w1, const float* __restrict__ b1,
    const float* __restrict__ w2, const float* __restrict__ b2,
    float* __restrict__ effw, float* __restrict__ cst)
{
    const int t = threadIdx.x;
    float local = 0.f;
    for (int c = t; c < IN1_C; c += 1024) {
        int j;
        if (c < NUM_BIN)                j = c;
        else if (c < NUM_BIN + NUM_CAT) j = NUM_BIN + ((c - NUM_BIN) >> 4);
        else                            j = 128 + ((c - NUM_BIN - NUM_CAT) >> 4);
        const float w2j = w2[j];
        effw[c] = w1[c] * w2j;
        local  += b1[c] * w2j;
    }
    if (t < IN2_C) local += b2[t];

    for (int off = 32; off > 0; off >>= 1)
        local += __shfl_down(local, off, 64);
    __shared__ float red[16];
    const int lane = t & 63, wid = t >> 6;
    if (lane == 0) red[wid] = local;
    __syncthreads();
    if (t == 0) {
        float s = 0.f;
        #pragma unroll
        for (int i = 0; i < 16; ++i) s += red[i];
        *cst = s;
    }
}

// ---------------------------------------------------------------------------
// Kernel 2: one wave per row. out[r] = dot(x[r,:], effw) + cst
// 4 waves/block; VGPR capped for 8 waves/SIMD occupancy (memory-bound: TLP
// over deep unroll). x is streamed once -> nontemporal loads; effw stays cached.
// ---------------------------------------------------------------------------
__global__ __launch_bounds__(256, 8) void pwl_main(
    const float* __restrict__ x, const float* __restrict__ effw,
    const float* __restrict__ cst, float* __restrict__ out)
{
    const int row  = blockIdx.x * 4 + (threadIdx.x >> 6);
    const int lane = threadIdx.x & 63;

    const f32x4* __restrict__ xr = (const f32x4*)(x + (size_t)row * IN1_C);
    const f32x4* __restrict__ w4 = (const f32x4*)effw;

    float s0 = 0.f, s1 = 0.f, s2 = 0.f, s3 = 0.f;

    // 20 full iterations of 64 float4, manually unrolled x4 with independent
    // accumulators (static indexing only -- no scratch).
    for (int k = 0; k < 20; k += 4) {
        const int i0 = lane + 64 * k;
        f32x4 a0 = __builtin_nontemporal_load(&xr[i0]);
        f32x4 w0 = w4[i0];
        f32x4 a1 = __builtin_nontemporal_load(&xr[i0 + 64]);
        f32x4 w1v = w4[i0 + 64];
        f32x4 a2 = __builtin_nontemporal_load(&xr[i0 + 128]);
        f32x4 w2v = w4[i0 + 128];
        f32x4 a3 = __builtin_nontemporal_load(&xr[i0 + 192]);
        f32x4 w3v = w4[i0 + 192];
        s0 += a0.x * w0.x + a0.y * w0.y + a0.z * w0.z + a0.w * w0.w;
        s1 += a1.x * w1v.x + a1.y * w1v.y + a1.z * w1v.z + a1.w * w1v.w;
        s2 += a2.x * w2v.x + a2.y * w2v.y + a2.z * w2v.z + a2.w * w2v.w;
        s3 += a3.x * w3v.x + a3.y * w3v.y + a3.z * w3v.z + a3.w * w3v.w;
    }
    // remainder: 1296 - 1280 = 16 float4
    if (lane < 16) {
        f32x4 a = __builtin_nontemporal_load(&xr[lane + 1280]);
        f32x4 w = w4[lane + 1280];
        s0 += a.x * w.x + a.y * w.y + a.z * w.z + a.w * w.w;
    }

    float sum = (s0 + s1) + (s2 + s3);
    for (int off = 32; off > 0; off >>= 1)
        sum += __shfl_down(sum, off, 64);

    if (lane == 0) out[row] = sum + *cst;
}

// ---------------------------------------------------------------------------
extern "C" void kernel_launch(void* const* d_in, const int* in_sizes, int n_in,
                              void* d_out, int out_size, void* d_ws, size_t ws_size,
                              hipStream_t stream)
{
    const float* x  = (const float*)d_in[0];   // (16384, 5184, 1) f32
    const float* w1 = (const float*)d_in[1];   // (5184,)
    const float* b1 = (const float*)d_in[2];   // (5184,)
    const float* w2 = (const float*)d_in[3];   // (384,)
    const float* b2 = (const float*)d_in[4];   // (384,)
    float* out = (float*)d_out;                // (16384,)

    float* effw = (float*)d_ws;                // 5184 floats
    float* cst  = effw + IN1_C;                // 1 float

    pwl_prep<<<1, 1024, 0, stream>>>(w1, b1, w2, b2, effw, cst);

    const int blocks = BATCH_C / 4;            // 4 rows (waves) per 256-thread block
    pwl_main<<<blocks, 256, 0, stream>>>(x, effw, cst, out);
}

// Round 4
// 64.397 us; speedup vs baseline: 2.4303x; 2.4303x over previous
//
#include <hip/hip_runtime.h>

// Problem constants (from reference)
constexpr int NUM_BIN  = 64;
constexpr int NUM_CAT  = 1024;   // 64 groups x 16
constexpr int NUM_NUM  = 4096;   // 256 groups x 16
constexpr int IN1_C    = NUM_BIN + NUM_CAT + NUM_NUM;   // 5184
constexpr int IN2_C    = 64 + 64 + 256;                 // 384
constexpr int BATCH_C  = 16384;
constexpr int NF4      = IN1_C / 4;                     // 1296 float4 per row

typedef float f32x4 __attribute__((ext_vector_type(4)));

// ---------------------------------------------------------------------------
// Kernel 1: eff_w[c] = w1[c] * w2[j(c)] ;  cst = sum_c b1[c]*w2[j(c)] + sum_j b2[j]
// Single block, 1024 threads. Fully overwrites its workspace region each call.
// ---------------------------------------------------------------------------
__global__ __launch_bounds__(1024) void pwl_prep(
    const float* __restrict__ w1, const float* __restrict__ b1,
    const float* __restrict__ w2, const float* __restrict__ b2,
    float* __restrict__ effw, float* __restrict__ cst)
{
    const int t = threadIdx.x;
    float local = 0.f;
    for (int c = t; c < IN1_C; c += 1024) {
        int j;
        if (c < NUM_BIN)                j = c;
        else if (c < NUM_BIN + NUM_CAT) j = NUM_BIN + ((c - NUM_BIN) >> 4);
        else                            j = 128 + ((c - NUM_BIN - NUM_CAT) >> 4);
        const float w2j = w2[j];
        effw[c] = w1[c] * w2j;
        local  += b1[c] * w2j;
    }
    if (t < IN2_C) local += b2[t];

    for (int off = 32; off > 0; off >>= 1)
        local += __shfl_down(local, off, 64);
    __shared__ float red[16];
    const int lane = t & 63, wid = t >> 6;
    if (lane == 0) red[wid] = local;
    __syncthreads();
    if (t == 0) {
        float s = 0.f;
        #pragma unroll
        for (int i = 0; i < 16; ++i) s += red[i];
        *cst = s;
    }
}

// ---------------------------------------------------------------------------
// Kernel 2: one wave per row. out[r] = dot(x[r,:], effw) + cst
// effw staged in LDS so the vmcnt queue carries ONLY the HBM x-stream
// (weight reads ride lgkmcnt). 4 waves/block, 4 independent accumulators,
// no VGPR cap (R3 lesson: capping to 8 waves/SIMD serialized the loads).
// ---------------------------------------------------------------------------
__global__ __launch_bounds__(256) void pwl_main(
    const float* __restrict__ x, const float* __restrict__ effw,
    const float* __restrict__ cst, float* __restrict__ out)
{
    __shared__ f32x4 wlds[NF4];          // 20.7 KB

    const int tid  = threadIdx.x;
    const int row  = blockIdx.x * 4 + (tid >> 6);
    const int lane = tid & 63;

    const f32x4* __restrict__ w4 = (const f32x4*)effw;
    // stage effw -> LDS (coalesced b128 writes, conflict-free)
    #pragma unroll
    for (int i = 0; i < 5; ++i)
        wlds[tid + 256 * i] = w4[tid + 256 * i];
    if (tid < NF4 - 1280)                // 16 remainder
        wlds[tid + 1280] = w4[tid + 1280];
    __syncthreads();

    const f32x4* __restrict__ xr = (const f32x4*)(x + (size_t)row * IN1_C);

    float s0 = 0.f, s1 = 0.f, s2 = 0.f, s3 = 0.f;
    #pragma unroll
    for (int k = 0; k < 20; k += 4) {
        const int i0 = lane + 64 * k;
        f32x4 a0 = xr[i0];
        f32x4 a1 = xr[i0 + 64];
        f32x4 a2 = xr[i0 + 128];
        f32x4 a3 = xr[i0 + 192];
        f32x4 w0 = wlds[i0];
        f32x4 w1v = wlds[i0 + 64];
        f32x4 w2v = wlds[i0 + 128];
        f32x4 w3v = wlds[i0 + 192];
        s0 += a0.x * w0.x + a0.y * w0.y + a0.z * w0.z + a0.w * w0.w;
        s1 += a1.x * w1v.x + a1.y * w1v.y + a1.z * w1v.z + a1.w * w1v.w;
        s2 += a2.x * w2v.x + a2.y * w2v.y + a2.z * w2v.z + a2.w * w2v.w;
        s3 += a3.x * w3v.x + a3.y * w3v.y + a3.z * w3v.z + a3.w * w3v.w;
    }
    // remainder: 1296 - 1280 = 16 float4
    if (lane < 16) {
        f32x4 a = xr[lane + 1280];
        f32x4 w = wlds[lane + 1280];
        s0 += a.x * w.x + a.y * w.y + a.z * w.z + a.w * w.w;
    }

    float sum = (s0 + s1) + (s2 + s3);
    for (int off = 32; off > 0; off >>= 1)
        sum += __shfl_down(sum, off, 64);

    if (lane == 0) out[row] = sum + *cst;
}

// ---------------------------------------------------------------------------
extern "C" void kernel_launch(void* const* d_in, const int* in_sizes, int n_in,
                              void* d_out, int out_size, void* d_ws, size_t ws_size,
                              hipStream_t stream)
{
    const float* x  = (const float*)d_in[0];   // (16384, 5184, 1) f32
    const float* w1 = (const float*)d_in[1];   // (5184,)
    const float* b1 = (const float*)d_in[2];   // (5184,)
    const float* w2 = (const float*)d_in[3];   // (384,)
    const float* b2 = (const float*)d_in[4];   // (384,)
    float* out = (float*)d_out;                // (16384,)

    float* effw = (float*)d_ws;                // 5184 floats
    float* cst  = effw + IN1_C;                // 1 float

    pwl_prep<<<1, 1024, 0, stream>>>(w1, b1, w2, b2, effw, cst);

    const int blocks = BATCH_C / 4;            // 4 rows (waves) per 256-thread block
    pwl_main<<<blocks, 256, 0, stream>>>(x, effw, cst, out);
}

// Round 5
// 60.941 us; speedup vs baseline: 2.5681x; 1.0567x over previous
//
#include <hip/hip_runtime.h>

// Problem constants (from reference)
constexpr int NUM_BIN  = 64;
constexpr int NUM_CAT  = 1024;   // 64 groups x 16
constexpr int NUM_NUM  = 4096;   // 256 groups x 16
constexpr int IN1_C    = NUM_BIN + NUM_CAT + NUM_NUM;   // 5184
constexpr int IN2_C    = 64 + 64 + 256;                 // 384
constexpr int BATCH_C  = 16384;
constexpr int NF4      = IN1_C / 4;                     // 1296 float4 per row

typedef float f32x4 __attribute__((ext_vector_type(4)));

// ---------------------------------------------------------------------------
// Single fused kernel. Per block (256 thr = 4 waves, 4 rows):
//   1) build effw[c] = w1[c]*w2[j(c)] into LDS (w1/w2 are L2-resident;
//      ~41 KB L2 traffic per block, overlapped with other blocks' HBM stream),
//      while accumulating cst = sum b1[c]*w2[j(c)] + sum b2  via block reduce
//      folded into the same staging barrier.
//   2) stream 4 rows of x (HBM, the real payload) against LDS weights.
// This deletes the serialized 1-block prep dispatch of R1-R4 (~5 us).
// ---------------------------------------------------------------------------
__global__ __launch_bounds__(256) void pwl_fused(
    const float* __restrict__ x,  const float* __restrict__ w1,
    const float* __restrict__ b1, const float* __restrict__ w2,
    const float* __restrict__ b2, float* __restrict__ out)
{
    __shared__ f32x4 wlds[NF4];          // 20.7 KB
    __shared__ float red[4];

    const int tid  = threadIdx.x;
    const int lane = tid & 63;
    const int wid  = tid >> 6;
    const int row  = blockIdx.x * 4 + wid;

    float* wl = (float*)wlds;

    // ---- stage effw into LDS + accumulate bias constant ----
    float partial = 0.f;
    #pragma unroll
    for (int i = 0; i < 20; ++i) {
        const int c = tid + 256 * i;
        int j;
        if (c < NUM_BIN)                j = c;
        else if (c < NUM_BIN + NUM_CAT) j = NUM_BIN + ((c - NUM_BIN) >> 4);
        else                            j = 128 + ((c - NUM_BIN - NUM_CAT) >> 4);
        const float w2j = w2[j];
        wl[c]    = w1[c] * w2j;
        partial += b1[c] * w2j;
    }
    if (tid < 64) {                      // channels 5120..5183 (all in num range)
        const int c = 5120 + tid;
        const float w2j = w2[128 + ((c - NUM_BIN - NUM_CAT) >> 4)];
        wl[c]    = w1[c] * w2j;
        partial += b1[c] * w2j;
    }
    partial += b2[tid] + ((tid < IN2_C - 256) ? b2[tid + 256] : 0.f);

    // wave reduce, stash per-wave partials; the trailing barrier covers both
    // the LDS weight table and red[].
    for (int off = 32; off > 0; off >>= 1)
        partial += __shfl_down(partial, off, 64);
    if (lane == 0) red[wid] = partial;
    __syncthreads();

    // ---- stream this wave's row ----
    const f32x4* __restrict__ xr = (const f32x4*)(x + (size_t)row * IN1_C);

    float s0 = 0.f, s1 = 0.f, s2 = 0.f, s3 = 0.f;
    #pragma unroll
    for (int k = 0; k < 20; k += 4) {
        const int i0 = lane + 64 * k;
        f32x4 a0 = xr[i0];
        f32x4 a1 = xr[i0 + 64];
        f32x4 a2 = xr[i0 + 128];
        f32x4 a3 = xr[i0 + 192];
        f32x4 w0 = wlds[i0];
        f32x4 w1v = wlds[i0 + 64];
        f32x4 w2v = wlds[i0 + 128];
        f32x4 w3v = wlds[i0 + 192];
        s0 += a0.x * w0.x + a0.y * w0.y + a0.z * w0.z + a0.w * w0.w;
        s1 += a1.x * w1v.x + a1.y * w1v.y + a1.z * w1v.z + a1.w * w1v.w;
        s2 += a2.x * w2v.x + a2.y * w2v.y + a2.z * w2v.z + a2.w * w2v.w;
        s3 += a3.x * w3v.x + a3.y * w3v.y + a3.z * w3v.z + a3.w * w3v.w;
    }
    // remainder: 1296 - 1280 = 16 float4
    if (lane < 16) {
        f32x4 a = xr[lane + 1280];
        f32x4 w = wlds[lane + 1280];
        s0 += a.x * w.x + a.y * w.y + a.z * w.z + a.w * w.w;
    }

    float sum = (s0 + s1) + (s2 + s3);
    for (int off = 32; off > 0; off >>= 1)
        sum += __shfl_down(sum, off, 64);

    if (lane == 0)
        out[row] = sum + (red[0] + red[1]) + (red[2] + red[3]);
}

// ---------------------------------------------------------------------------
extern "C" void kernel_launch(void* const* d_in, const int* in_sizes, int n_in,
                              void* d_out, int out_size, void* d_ws, size_t ws_size,
                              hipStream_t stream)
{
    const float* x  = (const float*)d_in[0];   // (16384, 5184, 1) f32
    const float* w1 = (const float*)d_in[1];   // (5184,)
    const float* b1 = (const float*)d_in[2];   // (5184,)
    const float* w2 = (const float*)d_in[3];   // (384,)
    const float* b2 = (const float*)d_in[4];   // (384,)
    float* out = (float*)d_out;                // (16384,)

    const int blocks = BATCH_C / 4;            // 4 rows (waves) per 256-thread block
    pwl_fused<<<blocks, 256, 0, stream>>>(x, w1, b1, w2, b2, out);
}

// Round 6
// 60.525 us; speedup vs baseline: 2.5857x; 1.0069x over previous
//
#include <hip/hip_runtime.h>

// Problem constants (from reference)
constexpr int NUM_BIN  = 64;
constexpr int NUM_CAT  = 1024;   // 64 groups x 16
constexpr int NUM_NUM  = 4096;   // 256 groups x 16
constexpr int IN1_C    = NUM_BIN + NUM_CAT + NUM_NUM;   // 5184
constexpr int IN2_C    = 64 + 64 + 256;                 // 384
constexpr int BATCH_C  = 16384;
constexpr int NF4      = IN1_C / 4;                     // 1296 float4 per row

constexpr int NBLK     = 1024;           // 4 blocks/CU -> ALL blocks co-resident
constexpr int NWAVE    = NBLK * 4;       // 4096 waves
constexpr int ROWS_PW  = BATCH_C / NWAVE; // 4 rows per wave

typedef float f32x4 __attribute__((ext_vector_type(4)));

// ---------------------------------------------------------------------------
// Single fused kernel, resident grid. Per block (256 thr = 4 waves):
//   1) build effw[c]=w1[c]*w2[j(c)] into LDS + block-reduce the bias constant
//      -- paid ONCE per block, all 1024 blocks co-resident (R5 paid it 16x/CU).
//   2) each wave grid-strides 4 rows of x: pure HBM b128 read stream vs LDS
//      weights, wave shuffle-reduce, one scalar store per row.
// ---------------------------------------------------------------------------
__global__ __launch_bounds__(256) void pwl_fused(
    const float* __restrict__ x,  const float* __restrict__ w1,
    const float* __restrict__ b1, const float* __restrict__ w2,
    const float* __restrict__ b2, float* __restrict__ out)
{
    __shared__ f32x4 wlds[NF4];          // 20.7 KB
    __shared__ float red[4];

    const int tid  = threadIdx.x;
    const int lane = tid & 63;
    const int wid  = tid >> 6;
    const int gwave = blockIdx.x * 4 + wid;

    float* wl = (float*)wlds;

    // ---- stage effw into LDS + accumulate bias constant ----
    float partial = 0.f;
    #pragma unroll
    for (int i = 0; i < 20; ++i) {
        const int c = tid + 256 * i;
        int j;
        if (c < NUM_BIN)                j = c;
        else if (c < NUM_BIN + NUM_CAT) j = NUM_BIN + ((c - NUM_BIN) >> 4);
        else                            j = 128 + ((c - NUM_BIN - NUM_CAT) >> 4);
        const float w2j = w2[j];
        wl[c]    = w1[c] * w2j;
        partial += b1[c] * w2j;
    }
    if (tid < 64) {                      // channels 5120..5183 (all in num range)
        const int c = 5120 + tid;
        const float w2j = w2[128 + ((c - NUM_BIN - NUM_CAT) >> 4)];
        wl[c]    = w1[c] * w2j;
        partial += b1[c] * w2j;
    }
    partial += b2[tid] + ((tid < IN2_C - 256) ? b2[tid + 256] : 0.f);

    for (int off = 32; off > 0; off >>= 1)
        partial += __shfl_down(partial, off, 64);
    if (lane == 0) red[wid] = partial;
    __syncthreads();                     // covers wlds and red

    const float cst = (red[0] + red[1]) + (red[2] + red[3]);

    // ---- stream ROWS_PW rows per wave ----
    #pragma unroll
    for (int rr = 0; rr < ROWS_PW; ++rr) {
        const int row = gwave + rr * NWAVE;
        const f32x4* __restrict__ xr = (const f32x4*)(x + (size_t)row * IN1_C);

        float s0 = 0.f, s1 = 0.f, s2 = 0.f, s3 = 0.f;
        #pragma unroll
        for (int k = 0; k < 20; k += 4) {
            const int i0 = lane + 64 * k;
            f32x4 a0 = xr[i0];
            f32x4 a1 = xr[i0 + 64];
            f32x4 a2 = xr[i0 + 128];
            f32x4 a3 = xr[i0 + 192];
            f32x4 w0 = wlds[i0];
            f32x4 w1v = wlds[i0 + 64];
            f32x4 w2v = wlds[i0 + 128];
            f32x4 w3v = wlds[i0 + 192];
            s0 += a0.x * w0.x + a0.y * w0.y + a0.z * w0.z + a0.w * w0.w;
            s1 += a1.x * w1v.x + a1.y * w1v.y + a1.z * w1v.z + a1.w * w1v.w;
            s2 += a2.x * w2v.x + a2.y * w2v.y + a2.z * w2v.z + a2.w * w2v.w;
            s3 += a3.x * w3v.x + a3.y * w3v.y + a3.z * w3v.z + a3.w * w3v.w;
        }
        // remainder: 1296 - 1280 = 16 float4
        if (lane < 16) {
            f32x4 a = xr[lane + 1280];
            f32x4 w = wlds[lane + 1280];
            s0 += a.x * w.x + a.y * w.y + a.z * w.z + a.w * w.w;
        }

        float sum = (s0 + s1) + (s2 + s3);
        for (int off = 32; off > 0; off >>= 1)
            sum += __shfl_down(sum, off, 64);

        if (lane == 0) out[row] = sum + cst;
    }
}

// ---------------------------------------------------------------------------
extern "C" void kernel_launch(void* const* d_in, const int* in_sizes, int n_in,
                              void* d_out, int out_size, void* d_ws, size_t ws_size,
                              hipStream_t stream)
{
    const float* x  = (const float*)d_in[0];   // (16384, 5184, 1) f32
    const float* w1 = (const float*)d_in[1];   // (5184,)
    const float* b1 = (const float*)d_in[2];   // (5184,)
    const float* w2 = (const float*)d_in[3];   // (384,)
    const float* b2 = (const float*)d_in[4];   // (384,)
    float* out = (float*)d_out;                // (16384,)

    pwl_fused<<<NBLK, 256, 0, stream>>>(x, w1, b1, w2, b2, out);
}